// Round 1
// baseline (673.613 us; speedup 1.0000x reference)
//
#include <hip/hip_runtime.h>
#include <math.h>

#define S_TOK 2048
#define H_DIM 1024
#define E_NUM 16
#define FF_DIM 1024
#define TOPK 4
#define CLIPV 7.0f
#define AUXC 0.02f
#define BK 32
#define NT (H_DIM / BK)

typedef short bf16x8 __attribute__((ext_vector_type(8)));
typedef float f32x4 __attribute__((ext_vector_type(4)));

__device__ __forceinline__ unsigned short f2bf(float f) {
  unsigned int u = __float_as_uint(f);
  u += 0x7fffu + ((u >> 16) & 1u);
  return (unsigned short)(u >> 16);
}

__device__ __forceinline__ void gload16(const void* g, void* l) {
  __builtin_amdgcn_global_load_lds((const __attribute__((address_space(1))) void*)g,
                                   (__attribute__((address_space(3))) void*)l, 16, 0, 0);
}

__device__ __forceinline__ int imin(int a, int b) { return a < b ? a : b; }

// ---------------- router: one wave per token ----------------
__global__ void router_kernel(const float* __restrict__ x, const float* __restrict__ rw,
                              const float* __restrict__ rb,
                              int* __restrict__ topk_i, float* __restrict__ topk_w,
                              int* __restrict__ counts, float* __restrict__ imp,
                              int* __restrict__ pos_cnt) {
  int tok = blockIdx.x * 4 + (threadIdx.x >> 6);
  int lane = threadIdx.x & 63;
  const float* xr = x + (size_t)tok * H_DIM;
  float p[E_NUM];
#pragma unroll
  for (int e = 0; e < E_NUM; ++e) p[e] = 0.f;
  for (int it = 0; it < H_DIM / 64; ++it) {
    float xv = xr[lane + it * 64];
#pragma unroll
    for (int e = 0; e < E_NUM; ++e) p[e] += xv * rw[e * H_DIM + lane + it * 64];
  }
#pragma unroll
  for (int e = 0; e < E_NUM; ++e) {
#pragma unroll
    for (int off = 32; off > 0; off >>= 1) p[e] += __shfl_xor(p[e], off);
  }
  if (lane == 0) {
    float lg[E_NUM];
    for (int e = 0; e < E_NUM; ++e) lg[e] = p[e] + rb[e];
    int idx[TOPK]; float val[TOPK];
    float tmp[E_NUM];
    for (int e = 0; e < E_NUM; ++e) tmp[e] = lg[e];
    for (int k = 0; k < TOPK; ++k) {
      float best = -INFINITY; int bi = 0;
      for (int e = 0; e < E_NUM; ++e) if (tmp[e] > best) { best = tmp[e]; bi = e; }
      val[k] = best; idx[k] = bi; tmp[bi] = -INFINITY;
    }
    // softmax over top-4 (val[0] is the max)
    float ssum = 0.f, wv[TOPK];
    for (int k = 0; k < TOPK; ++k) { wv[k] = expf(val[k] - val[0]); ssum += wv[k]; }
    for (int k = 0; k < TOPK; ++k) wv[k] /= ssum;
    // full softmax -> importance accumulation
    float se = 0.f;
    for (int e = 0; e < E_NUM; ++e) se += expf(lg[e] - val[0]);
    float inv = 1.f / se;
    for (int e = 0; e < E_NUM; ++e) atomicAdd(&imp[e], expf(lg[e] - val[0]) * inv);
    // argmax over the top-k *indices* (faithful to source)
    int mi = idx[0], pos = 0;
    for (int k = 1; k < TOPK; ++k) if (idx[k] > mi) { mi = idx[k]; pos = k; }
    atomicAdd(&pos_cnt[pos], 1);
    for (int k = 0; k < TOPK; ++k) {
      topk_i[tok * TOPK + k] = idx[k];
      topk_w[tok * TOPK + k] = wv[k];
      atomicAdd(&counts[idx[k]], 1);
    }
  }
}

// ---------------- exclusive scan over 16 expert counts ----------------
__global__ void scan_kernel(const int* __restrict__ counts, int* __restrict__ offsets) {
  if (threadIdx.x == 0) {
    int off = 0;
    for (int e = 0; e < E_NUM; ++e) { offsets[e] = off; off += counts[e]; }
    offsets[E_NUM] = off;
  }
}

// ---------------- build grouped token lists ----------------
__global__ void assign_kernel(const int* __restrict__ topk_i, const float* __restrict__ topk_w,
                              const int* __restrict__ offsets, int* __restrict__ cursor,
                              int* __restrict__ tok_list, float* __restrict__ w_list) {
  int t = blockIdx.x * blockDim.x + threadIdx.x;
  if (t >= S_TOK) return;
  for (int k = 0; k < TOPK; ++k) {
    int e = topk_i[t * TOPK + k];
    int slot = offsets[e] + atomicAdd(&cursor[e], 1);
    tok_list[slot] = t;
    w_list[slot] = topk_w[t * TOPK + k];
  }
}

// ---------------- x fp32 -> bf16 ----------------
__global__ void convert_x_kernel(const float* __restrict__ x, unsigned short* __restrict__ xb) {
  int i = blockIdx.x * blockDim.x + threadIdx.x;  // one per 4 elems
  float4 v = ((const float4*)x)[i];
  ushort4 o;
  o.x = f2bf(v.x); o.y = f2bf(v.y); o.z = f2bf(v.z); o.w = f2bf(v.w);
  ((ushort4*)xb)[i] = o;
}

// ---------------- tiled transpose fp32 [R][C] -> bf16 [C][R], per expert slab ----------------
__global__ void transpose_kernel(const float* __restrict__ in, unsigned short* __restrict__ out,
                                 int R, int C) {
  __shared__ float tile[64][65];
  int e = blockIdx.z;
  in  += (size_t)e * R * C;
  out += (size_t)e * R * C;
  int r0 = blockIdx.y * 64, c0 = blockIdx.x * 64;
  int tx = threadIdx.x & 15, ty = threadIdx.x >> 4;
#pragma unroll
  for (int j = 0; j < 4; ++j) {
    int r = ty + j * 16;
    float4 v = *(const float4*)&in[(size_t)(r0 + r) * C + c0 + tx * 4];
    tile[r][tx * 4 + 0] = v.x; tile[r][tx * 4 + 1] = v.y;
    tile[r][tx * 4 + 2] = v.z; tile[r][tx * 4 + 3] = v.w;
  }
  __syncthreads();
#pragma unroll
  for (int j = 0; j < 4; ++j) {
    int c = ty + j * 16;
    ushort4 o;
    o.x = f2bf(tile[tx * 4 + 0][c]);
    o.y = f2bf(tile[tx * 4 + 1][c]);
    o.z = f2bf(tile[tx * 4 + 2][c]);
    o.w = f2bf(tile[tx * 4 + 3][c]);
    *(ushort4*)&out[(size_t)(c0 + c) * R + r0 + tx * 4] = o;
  }
}

// ---------------- GEMM1: act = silu(clip(gate)) * clip(up), grouped per expert ----------------
// A: gathered token rows of xb [S][H]; B: winT [E][2FF][H] (row-major K). Tile M=128, 64 act cols.
__global__ __launch_bounds__(256) void gemm1_kernel(
    const unsigned short* __restrict__ xb, const unsigned short* __restrict__ winT,
    const float* __restrict__ b_in, const int* __restrict__ offsets,
    const int* __restrict__ tok_list, unsigned short* __restrict__ act) {
  __shared__ unsigned short ldsA[2][128 * BK];
  __shared__ unsigned short ldsB[2][128 * BK];
  const int e = blockIdx.z;
  const int base = offsets[e];
  const int cnt = offsets[e + 1] - base;
  const int mt = blockIdx.y;
  if (mt * 128 >= cnt) return;
  const int n0 = blockIdx.x * 64;
  const int tid = threadIdx.x, w = tid >> 6, lane = tid & 63;

  const int rA0 = (w * 2 + 0) * 16 + (lane >> 2);
  const int rA1 = rA0 + 16;
  const int t0 = tok_list[base + imin(mt * 128 + rA0, cnt - 1)];
  const int t1 = tok_list[base + imin(mt * 128 + rA1, cnt - 1)];
  const unsigned short* gA0 = xb + (size_t)t0 * H_DIM + (lane & 3) * 8;
  const unsigned short* gA1 = xb + (size_t)t1 * H_DIM + (lane & 3) * 8;
  const int nb0 = (rA0 < 64) ? (n0 + rA0) : (FF_DIM + n0 + rA0 - 64);
  const int nb1 = (rA1 < 64) ? (n0 + rA1) : (FF_DIM + n0 + rA1 - 64);
  const unsigned short* we = winT + (size_t)e * 2 * FF_DIM * H_DIM;
  const unsigned short* gB0 = we + (size_t)nb0 * H_DIM + (lane & 3) * 8;
  const unsigned short* gB1 = we + (size_t)nb1 * H_DIM + (lane & 3) * 8;

  f32x4 acc[2][8];
#pragma unroll
  for (int m = 0; m < 2; ++m)
#pragma unroll
    for (int n = 0; n < 8; ++n) acc[m][n] = (f32x4){0.f, 0.f, 0.f, 0.f};

#define STAGE1(buf, k0)                                            \
  do {                                                             \
    gload16(gA0 + (k0), &ldsA[buf][(w * 2 + 0) * 16 * BK]);        \
    gload16(gA1 + (k0), &ldsA[buf][(w * 2 + 1) * 16 * BK]);        \
    gload16(gB0 + (k0), &ldsB[buf][(w * 2 + 0) * 16 * BK]);        \
    gload16(gB1 + (k0), &ldsB[buf][(w * 2 + 1) * 16 * BK]);        \
  } while (0)

  STAGE1(0, 0);
  __syncthreads();
  int buf = 0;
  const int ko = (lane >> 4) * 8;
  for (int kt = 0; kt < NT; ++kt) {
    if (kt + 1 < NT) STAGE1(buf ^ 1, (kt + 1) * BK);
    bf16x8 a[2], b[8];
#pragma unroll
    for (int mf = 0; mf < 2; ++mf)
      a[mf] = *(const bf16x8*)&ldsA[buf][(w * 32 + mf * 16 + (lane & 15)) * BK + ko];
#pragma unroll
    for (int nf = 0; nf < 8; ++nf)
      b[nf] = *(const bf16x8*)&ldsB[buf][(nf * 16 + (lane & 15)) * BK + ko];
#pragma unroll
    for (int mf = 0; mf < 2; ++mf)
#pragma unroll
      for (int nf = 0; nf < 8; ++nf)
        acc[mf][nf] = __builtin_amdgcn_mfma_f32_16x16x32_bf16(a[mf], b[nf], acc[mf][nf], 0, 0, 0);
    __syncthreads();
    buf ^= 1;
  }

  const float* bin = b_in + (size_t)e * 2 * FF_DIM;
#pragma unroll
  for (int mf = 0; mf < 2; ++mf) {
    int rbase = w * 32 + mf * 16 + (lane >> 4) * 4;
#pragma unroll
    for (int nf = 0; nf < 4; ++nf) {
      int f = n0 + nf * 16 + (lane & 15);
      float bu = bin[f], bg = bin[FF_DIM + f];
#pragma unroll
      for (int i = 0; i < 4; ++i) {
        int mrow = mt * 128 + rbase + i;
        if (mrow < cnt) {
          float up = acc[mf][nf][i] + bu;
          float gt = acc[mf][nf + 4][i] + bg;
          up = fminf(fmaxf(up, -CLIPV), CLIPV);
          gt = fminf(fmaxf(gt, -CLIPV), CLIPV);
          float av = (gt / (1.f + expf(-gt))) * up;
          act[(size_t)(base + mrow) * FF_DIM + f] = f2bf(av);
        }
      }
    }
  }
}

// ---------------- GEMM2: out[tok] += w * (act @ W_out^T + b_out), grouped ----------------
__global__ __launch_bounds__(256) void gemm2_kernel(
    const unsigned short* __restrict__ act, const unsigned short* __restrict__ woutT,
    const float* __restrict__ b_out, const int* __restrict__ offsets,
    const int* __restrict__ tok_list, const float* __restrict__ w_list,
    float* __restrict__ out) {
  __shared__ unsigned short ldsA[2][128 * BK];
  __shared__ unsigned short ldsB[2][128 * BK];
  const int e = blockIdx.z;
  const int base = offsets[e];
  const int cnt = offsets[e + 1] - base;
  const int mt = blockIdx.y;
  if (mt * 128 >= cnt) return;
  const int n0 = blockIdx.x * 128;
  const int tid = threadIdx.x, w = tid >> 6, lane = tid & 63;

  const int rA0 = (w * 2 + 0) * 16 + (lane >> 2);
  const int rA1 = rA0 + 16;
  const int m0_ = imin(mt * 128 + rA0, cnt - 1);
  const int m1_ = imin(mt * 128 + rA1, cnt - 1);
  const unsigned short* gA0 = act + (size_t)(base + m0_) * FF_DIM + (lane & 3) * 8;
  const unsigned short* gA1 = act + (size_t)(base + m1_) * FF_DIM + (lane & 3) * 8;
  const unsigned short* we = woutT + (size_t)e * H_DIM * FF_DIM;
  const unsigned short* gB0 = we + (size_t)(n0 + rA0) * FF_DIM + (lane & 3) * 8;
  const unsigned short* gB1 = we + (size_t)(n0 + rA1) * FF_DIM + (lane & 3) * 8;

  f32x4 acc[4][4];
#pragma unroll
  for (int m = 0; m < 4; ++m)
#pragma unroll
    for (int n = 0; n < 4; ++n) acc[m][n] = (f32x4){0.f, 0.f, 0.f, 0.f};

#define STAGE2(buf, k0)                                            \
  do {                                                             \
    gload16(gA0 + (k0), &ldsA[buf][(w * 2 + 0) * 16 * BK]);        \
    gload16(gA1 + (k0), &ldsA[buf][(w * 2 + 1) * 16 * BK]);        \
    gload16(gB0 + (k0), &ldsB[buf][(w * 2 + 0) * 16 * BK]);        \
    gload16(gB1 + (k0), &ldsB[buf][(w * 2 + 1) * 16 * BK]);        \
  } while (0)

  STAGE2(0, 0);
  __syncthreads();
  int buf = 0;
  const int ko = (lane >> 4) * 8;
  const int wm = (w >> 1) * 64, wn = (w & 1) * 64;
  for (int kt = 0; kt < FF_DIM / BK; ++kt) {
    if (kt + 1 < FF_DIM / BK) STAGE2(buf ^ 1, (kt + 1) * BK);
    bf16x8 a[4], b[4];
#pragma unroll
    for (int mi = 0; mi < 4; ++mi)
      a[mi] = *(const bf16x8*)&ldsA[buf][(wm + mi * 16 + (lane & 15)) * BK + ko];
#pragma unroll
    for (int ni = 0; ni < 4; ++ni)
      b[ni] = *(const bf16x8*)&ldsB[buf][(wn + ni * 16 + (lane & 15)) * BK + ko];
#pragma unroll
    for (int mi = 0; mi < 4; ++mi)
#pragma unroll
      for (int ni = 0; ni < 4; ++ni)
        acc[mi][ni] = __builtin_amdgcn_mfma_f32_16x16x32_bf16(a[mi], b[ni], acc[mi][ni], 0, 0, 0);
    __syncthreads();
    buf ^= 1;
  }

  const float* bo = b_out + (size_t)e * H_DIM;
#pragma unroll
  for (int mi = 0; mi < 4; ++mi) {
#pragma unroll
    for (int i = 0; i < 4; ++i) {
      int mrow = mt * 128 + wm + mi * 16 + (lane >> 4) * 4 + i;
      if (mrow < cnt) {
        int slot = base + mrow;
        int t = tok_list[slot];
        float wt = w_list[slot];
#pragma unroll
        for (int ni = 0; ni < 4; ++ni) {
          int h = n0 + wn + ni * 16 + (lane & 15);
          atomicAdd(&out[(size_t)t * H_DIM + h], wt * (acc[mi][ni][i] + bo[h]));
        }
      }
    }
  }
}

// ---------------- aux loss finalize ----------------
__global__ void finalize_kernel(const float* __restrict__ imp, const int* __restrict__ pos_cnt,
                                float* __restrict__ out_aux) {
  if (threadIdx.x == 0) {
    float s = 0.f;
    for (int p = 0; p < TOPK; ++p)
      s += (imp[p] / (float)S_TOK) * ((float)pos_cnt[p] / (float)S_TOK);
    *out_aux = AUXC * (float)E_NUM * s;
  }
}

extern "C" void kernel_launch(void* const* d_in, const int* in_sizes, int n_in,
                              void* d_out, int out_size, void* d_ws, size_t ws_size,
                              hipStream_t stream) {
  const float* x     = (const float*)d_in[0];
  const float* W_in  = (const float*)d_in[1];
  const float* b_in  = (const float*)d_in[2];
  const float* W_out = (const float*)d_in[3];
  const float* b_out = (const float*)d_in[4];
  const float* rw    = (const float*)d_in[5];
  const float* rb    = (const float*)d_in[6];
  float* out = (float*)d_out;

  char* ws = (char*)d_ws;
  size_t off = 0;
  auto alloc = [&](size_t bytes) {
    void* p = ws + off;
    off = (off + bytes + 255) & ~(size_t)255;
    return p;
  };
  unsigned short* xb    = (unsigned short*)alloc((size_t)S_TOK * H_DIM * 2);
  unsigned short* winT  = (unsigned short*)alloc((size_t)E_NUM * 2 * FF_DIM * H_DIM * 2);
  unsigned short* woutT = (unsigned short*)alloc((size_t)E_NUM * H_DIM * FF_DIM * 2);
  unsigned short* act   = (unsigned short*)alloc((size_t)S_TOK * TOPK * FF_DIM * 2);
  int*   topk_i  = (int*)alloc(S_TOK * TOPK * 4);
  float* topk_w  = (float*)alloc(S_TOK * TOPK * 4);
  int*   tok_list= (int*)alloc(S_TOK * TOPK * 4);
  float* w_list  = (float*)alloc(S_TOK * TOPK * 4);
  // zeroed control block: counts[16], cursor[16], pos_cnt[16] ints, imp[16] floats
  int* ctrl = (int*)alloc(64 * 4);
  int* counts = ctrl;
  int* cursor = ctrl + 16;
  int* pos_cnt = ctrl + 32;
  float* imp = (float*)(ctrl + 48);
  int* offsets = (int*)alloc(32 * 4);

  hipMemsetAsync(d_out, 0, (size_t)out_size * sizeof(float), stream);
  hipMemsetAsync(ctrl, 0, 64 * 4, stream);

  router_kernel<<<S_TOK / 4, 256, 0, stream>>>(x, rw, rb, topk_i, topk_w, counts, imp, pos_cnt);
  convert_x_kernel<<<(S_TOK * H_DIM / 4) / 256, 256, 0, stream>>>(x, xb);
  transpose_kernel<<<dim3(2 * FF_DIM / 64, H_DIM / 64, E_NUM), 256, 0, stream>>>(W_in, winT, H_DIM, 2 * FF_DIM);
  transpose_kernel<<<dim3(H_DIM / 64, FF_DIM / 64, E_NUM), 256, 0, stream>>>(W_out, woutT, FF_DIM, H_DIM);
  scan_kernel<<<1, 64, 0, stream>>>(counts, offsets);
  assign_kernel<<<(S_TOK + 255) / 256, 256, 0, stream>>>(topk_i, topk_w, offsets, cursor, tok_list, w_list);
  gemm1_kernel<<<dim3(FF_DIM / 64, S_TOK / 128, E_NUM), 256, 0, stream>>>(xb, winT, b_in, offsets, tok_list, act);
  gemm2_kernel<<<dim3(H_DIM / 128, S_TOK / 128, E_NUM), 256, 0, stream>>>(act, woutT, b_out, offsets, tok_list, w_list, out);
  finalize_kernel<<<1, 64, 0, stream>>>(imp, pos_cnt, out + (size_t)S_TOK * H_DIM);
}

// Round 2
// 228.473 us; speedup vs baseline: 2.9483x; 2.9483x over previous
//
#include <hip/hip_runtime.h>
#include <math.h>

#define S_TOK 2048
#define H_DIM 1024
#define E_NUM 16
#define FF_DIM 1024
#define TOPK 4
#define CLIPV 7.0f
#define AUXC 0.02f
#define BK 32
#define NT (H_DIM / BK)

typedef short bf16x8 __attribute__((ext_vector_type(8)));
typedef float f32x4 __attribute__((ext_vector_type(4)));

__device__ __forceinline__ unsigned short f2bf(float f) {
  unsigned int u = __float_as_uint(f);
  u += 0x7fffu + ((u >> 16) & 1u);
  return (unsigned short)(u >> 16);
}

__device__ __forceinline__ void gload16(const void* g, void* l) {
  __builtin_amdgcn_global_load_lds((const __attribute__((address_space(1))) void*)g,
                                   (__attribute__((address_space(3))) void*)l, 16, 0, 0);
}

__device__ __forceinline__ int imin(int a, int b) { return a < b ? a : b; }

// ---------------- router logits: one wave per token, no atomics ----------------
__global__ void logits_kernel(const float* __restrict__ x, const float* __restrict__ rw,
                              const float* __restrict__ rb, float* __restrict__ logits) {
  int tok = blockIdx.x * 4 + (threadIdx.x >> 6);
  int lane = threadIdx.x & 63;
  const float* xr = x + (size_t)tok * H_DIM;
  float p[E_NUM];
#pragma unroll
  for (int e = 0; e < E_NUM; ++e) p[e] = 0.f;
  for (int it = 0; it < H_DIM / 64; ++it) {
    float xv = xr[lane + it * 64];
#pragma unroll
    for (int e = 0; e < E_NUM; ++e) p[e] += xv * rw[e * H_DIM + lane + it * 64];
  }
#pragma unroll
  for (int e = 0; e < E_NUM; ++e) {
#pragma unroll
    for (int off = 32; off > 0; off >>= 1) p[e] += __shfl_xor(p[e], off);
  }
  if (lane == 0) {
    float4* lp = (float4*)&logits[tok * E_NUM];
#pragma unroll
    for (int q = 0; q < 4; ++q)
      lp[q] = make_float4(p[q * 4 + 0] + rb[q * 4 + 0], p[q * 4 + 1] + rb[q * 4 + 1],
                          p[q * 4 + 2] + rb[q * 4 + 2], p[q * 4 + 3] + rb[q * 4 + 3]);
  }
}

// ---------------- top-k + aux stats: one thread per token, LDS-aggregated atomics ----------------
__global__ __launch_bounds__(256) void topk_kernel(const float* __restrict__ logits,
                                                   int* __restrict__ topk_i, float* __restrict__ topk_w,
                                                   int* __restrict__ counts, float* __restrict__ imp,
                                                   int* __restrict__ pos_cnt) {
  __shared__ float s_imp[E_NUM];
  __shared__ int s_cnt[E_NUM];
  __shared__ int s_pos[TOPK];
  int tid = threadIdx.x;
  if (tid < E_NUM) { s_imp[tid] = 0.f; s_cnt[tid] = 0; }
  if (tid < TOPK) s_pos[tid] = 0;
  __syncthreads();

  int t = blockIdx.x * 256 + tid;
  float lg[E_NUM];
  {
    const float4* lp = (const float4*)&logits[t * E_NUM];
#pragma unroll
    for (int q = 0; q < 4; ++q) {
      float4 v = lp[q];
      lg[q * 4 + 0] = v.x; lg[q * 4 + 1] = v.y; lg[q * 4 + 2] = v.z; lg[q * 4 + 3] = v.w;
    }
  }
  // top-4 selection (strict >, ties -> lowest index; matches jax.lax.top_k)
  int idx[TOPK]; float val[TOPK];
  float tmp[E_NUM];
#pragma unroll
  for (int e = 0; e < E_NUM; ++e) tmp[e] = lg[e];
#pragma unroll
  for (int k = 0; k < TOPK; ++k) {
    float best = -INFINITY; int bi = 0;
#pragma unroll
    for (int e = 0; e < E_NUM; ++e) if (tmp[e] > best) { best = tmp[e]; bi = e; }
    val[k] = best; idx[k] = bi; tmp[bi] = -INFINITY;
  }
  // softmax over top-4 (val[0] is max)
  float ssum = 0.f, wv[TOPK];
#pragma unroll
  for (int k = 0; k < TOPK; ++k) { wv[k] = expf(val[k] - val[0]); ssum += wv[k]; }
#pragma unroll
  for (int k = 0; k < TOPK; ++k) wv[k] /= ssum;
#pragma unroll
  for (int k = 0; k < TOPK; ++k) {
    topk_i[t * TOPK + k] = idx[k];
    topk_w[t * TOPK + k] = wv[k];
  }
  // full softmax probs (importance contribution)
  float se = 0.f, pr[E_NUM];
#pragma unroll
  for (int e = 0; e < E_NUM; ++e) { pr[e] = expf(lg[e] - val[0]); se += pr[e]; }
  float inv = 1.f / se;
  // argmax over the top-k *indices* (position of largest expert index; first on ties)
  int mi = idx[0], pos = 0;
#pragma unroll
  for (int k = 1; k < TOPK; ++k) if (idx[k] > mi) { mi = idx[k]; pos = k; }

  // wave-level reductions, then lane0 -> LDS
  int lane = tid & 63;
#pragma unroll
  for (int e = 0; e < E_NUM; ++e) {
    float v = pr[e] * inv;
    int c = (idx[0] == e) + (idx[1] == e) + (idx[2] == e) + (idx[3] == e);
#pragma unroll
    for (int off = 32; off > 0; off >>= 1) {
      v += __shfl_xor(v, off);
      c += __shfl_xor(c, off);
    }
    if (lane == 0) {
      atomicAdd(&s_imp[e], v);
      atomicAdd(&s_cnt[e], c);
    }
  }
#pragma unroll
  for (int k = 0; k < TOPK; ++k) {
    int pc = (pos == k) ? 1 : 0;
#pragma unroll
    for (int off = 32; off > 0; off >>= 1) pc += __shfl_xor(pc, off);
    if (lane == 0) atomicAdd(&s_pos[k], pc);
  }
  __syncthreads();
  if (tid < E_NUM) {
    atomicAdd(&imp[tid], s_imp[tid]);
    atomicAdd(&counts[tid], s_cnt[tid]);
  }
  if (tid < TOPK) atomicAdd(&pos_cnt[tid], s_pos[tid]);
}

// ---------------- exclusive scan over 16 expert counts ----------------
__global__ void scan_kernel(const int* __restrict__ counts, int* __restrict__ offsets) {
  if (threadIdx.x == 0) {
    int off = 0;
    for (int e = 0; e < E_NUM; ++e) { offsets[e] = off; off += counts[e]; }
    offsets[E_NUM] = off;
  }
}

// ---------------- build grouped token lists (LDS-aggregated cursors) ----------------
__global__ __launch_bounds__(256) void assign_kernel(
    const int* __restrict__ topk_i, const float* __restrict__ topk_w,
    const int* __restrict__ offsets, int* __restrict__ cursor,
    int* __restrict__ tok_list, float* __restrict__ w_list) {
  __shared__ int s_cnt[E_NUM];
  __shared__ int s_base[E_NUM];
  int tid = threadIdx.x;
  if (tid < E_NUM) s_cnt[tid] = 0;
  __syncthreads();
  int t = blockIdx.x * 256 + tid;
  int e[TOPK], lslot[TOPK];
#pragma unroll
  for (int k = 0; k < TOPK; ++k) {
    e[k] = topk_i[t * TOPK + k];
    lslot[k] = atomicAdd(&s_cnt[e[k]], 1);
  }
  __syncthreads();
  if (tid < E_NUM) s_base[tid] = atomicAdd(&cursor[tid], s_cnt[tid]);
  __syncthreads();
#pragma unroll
  for (int k = 0; k < TOPK; ++k) {
    int slot = offsets[e[k]] + s_base[e[k]] + lslot[k];
    tok_list[slot] = t;
    w_list[slot] = topk_w[t * TOPK + k];
  }
}

// ---------------- x fp32 -> bf16 ----------------
__global__ void convert_x_kernel(const float* __restrict__ x, unsigned short* __restrict__ xb) {
  int i = blockIdx.x * blockDim.x + threadIdx.x;  // one per 4 elems
  float4 v = ((const float4*)x)[i];
  ushort4 o;
  o.x = f2bf(v.x); o.y = f2bf(v.y); o.z = f2bf(v.z); o.w = f2bf(v.w);
  ((ushort4*)xb)[i] = o;
}

// ---------------- tiled transpose fp32 [R][C] -> bf16 [C][R], per expert slab ----------------
__global__ void transpose_kernel(const float* __restrict__ in, unsigned short* __restrict__ out,
                                 int R, int C) {
  __shared__ float tile[64][65];
  int e = blockIdx.z;
  in  += (size_t)e * R * C;
  out += (size_t)e * R * C;
  int r0 = blockIdx.y * 64, c0 = blockIdx.x * 64;
  int tx = threadIdx.x & 15, ty = threadIdx.x >> 4;
#pragma unroll
  for (int j = 0; j < 4; ++j) {
    int r = ty + j * 16;
    float4 v = *(const float4*)&in[(size_t)(r0 + r) * C + c0 + tx * 4];
    tile[r][tx * 4 + 0] = v.x; tile[r][tx * 4 + 1] = v.y;
    tile[r][tx * 4 + 2] = v.z; tile[r][tx * 4 + 3] = v.w;
  }
  __syncthreads();
#pragma unroll
  for (int j = 0; j < 4; ++j) {
    int c = ty + j * 16;
    ushort4 o;
    o.x = f2bf(tile[tx * 4 + 0][c]);
    o.y = f2bf(tile[tx * 4 + 1][c]);
    o.z = f2bf(tile[tx * 4 + 2][c]);
    o.w = f2bf(tile[tx * 4 + 3][c]);
    *(ushort4*)&out[(size_t)(c0 + c) * R + r0 + tx * 4] = o;
  }
}

// ---------------- GEMM1: act = silu(clip(gate)) * clip(up), grouped per expert ----------------
__global__ __launch_bounds__(256) void gemm1_kernel(
    const unsigned short* __restrict__ xb, const unsigned short* __restrict__ winT,
    const float* __restrict__ b_in, const int* __restrict__ offsets,
    const int* __restrict__ tok_list, unsigned short* __restrict__ act) {
  __shared__ unsigned short ldsA[2][128 * BK];
  __shared__ unsigned short ldsB[2][128 * BK];
  const int e = blockIdx.z;
  const int base = offsets[e];
  const int cnt = offsets[e + 1] - base;
  const int mt = blockIdx.y;
  if (mt * 128 >= cnt) return;
  const int n0 = blockIdx.x * 64;
  const int tid = threadIdx.x, w = tid >> 6, lane = tid & 63;

  const int rA0 = (w * 2 + 0) * 16 + (lane >> 2);
  const int rA1 = rA0 + 16;
  const int t0 = tok_list[base + imin(mt * 128 + rA0, cnt - 1)];
  const int t1 = tok_list[base + imin(mt * 128 + rA1, cnt - 1)];
  const unsigned short* gA0 = xb + (size_t)t0 * H_DIM + (lane & 3) * 8;
  const unsigned short* gA1 = xb + (size_t)t1 * H_DIM + (lane & 3) * 8;
  const int nb0 = (rA0 < 64) ? (n0 + rA0) : (FF_DIM + n0 + rA0 - 64);
  const int nb1 = (rA1 < 64) ? (n0 + rA1) : (FF_DIM + n0 + rA1 - 64);
  const unsigned short* we = winT + (size_t)e * 2 * FF_DIM * H_DIM;
  const unsigned short* gB0 = we + (size_t)nb0 * H_DIM + (lane & 3) * 8;
  const unsigned short* gB1 = we + (size_t)nb1 * H_DIM + (lane & 3) * 8;

  f32x4 acc[2][8];
#pragma unroll
  for (int m = 0; m < 2; ++m)
#pragma unroll
    for (int n = 0; n < 8; ++n) acc[m][n] = (f32x4){0.f, 0.f, 0.f, 0.f};

#define STAGE1(buf, k0)                                            \
  do {                                                             \
    gload16(gA0 + (k0), &ldsA[buf][(w * 2 + 0) * 16 * BK]);        \
    gload16(gA1 + (k0), &ldsA[buf][(w * 2 + 1) * 16 * BK]);        \
    gload16(gB0 + (k0), &ldsB[buf][(w * 2 + 0) * 16 * BK]);        \
    gload16(gB1 + (k0), &ldsB[buf][(w * 2 + 1) * 16 * BK]);        \
  } while (0)

  STAGE1(0, 0);
  __syncthreads();
  int buf = 0;
  const int ko = (lane >> 4) * 8;
  for (int kt = 0; kt < NT; ++kt) {
    if (kt + 1 < NT) STAGE1(buf ^ 1, (kt + 1) * BK);
    bf16x8 a[2], b[8];
#pragma unroll
    for (int mf = 0; mf < 2; ++mf)
      a[mf] = *(const bf16x8*)&ldsA[buf][(w * 32 + mf * 16 + (lane & 15)) * BK + ko];
#pragma unroll
    for (int nf = 0; nf < 8; ++nf)
      b[nf] = *(const bf16x8*)&ldsB[buf][(nf * 16 + (lane & 15)) * BK + ko];
#pragma unroll
    for (int mf = 0; mf < 2; ++mf)
#pragma unroll
      for (int nf = 0; nf < 8; ++nf)
        acc[mf][nf] = __builtin_amdgcn_mfma_f32_16x16x32_bf16(a[mf], b[nf], acc[mf][nf], 0, 0, 0);
    __syncthreads();
    buf ^= 1;
  }

  const float* bin = b_in + (size_t)e * 2 * FF_DIM;
#pragma unroll
  for (int mf = 0; mf < 2; ++mf) {
    int rbase = w * 32 + mf * 16 + (lane >> 4) * 4;
#pragma unroll
    for (int nf = 0; nf < 4; ++nf) {
      int f = n0 + nf * 16 + (lane & 15);
      float bu = bin[f], bg = bin[FF_DIM + f];
#pragma unroll
      for (int i = 0; i < 4; ++i) {
        int mrow = mt * 128 + rbase + i;
        if (mrow < cnt) {
          float up = acc[mf][nf][i] + bu;
          float gt = acc[mf][nf + 4][i] + bg;
          up = fminf(fmaxf(up, -CLIPV), CLIPV);
          gt = fminf(fmaxf(gt, -CLIPV), CLIPV);
          float av = (gt / (1.f + expf(-gt))) * up;
          act[(size_t)(base + mrow) * FF_DIM + f] = f2bf(av);
        }
      }
    }
  }
}

// ---------------- GEMM2: out[tok] += w * (act @ W_out^T + b_out), grouped ----------------
__global__ __launch_bounds__(256) void gemm2_kernel(
    const unsigned short* __restrict__ act, const unsigned short* __restrict__ woutT,
    const float* __restrict__ b_out, const int* __restrict__ offsets,
    const int* __restrict__ tok_list, const float* __restrict__ w_list,
    float* __restrict__ out) {
  __shared__ unsigned short ldsA[2][128 * BK];
  __shared__ unsigned short ldsB[2][128 * BK];
  const int e = blockIdx.z;
  const int base = offsets[e];
  const int cnt = offsets[e + 1] - base;
  const int mt = blockIdx.y;
  if (mt * 128 >= cnt) return;
  const int n0 = blockIdx.x * 128;
  const int tid = threadIdx.x, w = tid >> 6, lane = tid & 63;

  const int rA0 = (w * 2 + 0) * 16 + (lane >> 2);
  const int rA1 = rA0 + 16;
  const int m0_ = imin(mt * 128 + rA0, cnt - 1);
  const int m1_ = imin(mt * 128 + rA1, cnt - 1);
  const unsigned short* gA0 = act + (size_t)(base + m0_) * FF_DIM + (lane & 3) * 8;
  const unsigned short* gA1 = act + (size_t)(base + m1_) * FF_DIM + (lane & 3) * 8;
  const unsigned short* we = woutT + (size_t)e * H_DIM * FF_DIM;
  const unsigned short* gB0 = we + (size_t)(n0 + rA0) * FF_DIM + (lane & 3) * 8;
  const unsigned short* gB1 = we + (size_t)(n0 + rA1) * FF_DIM + (lane & 3) * 8;

  f32x4 acc[4][4];
#pragma unroll
  for (int m = 0; m < 4; ++m)
#pragma unroll
    for (int n = 0; n < 4; ++n) acc[m][n] = (f32x4){0.f, 0.f, 0.f, 0.f};

#define STAGE2(buf, k0)                                            \
  do {                                                             \
    gload16(gA0 + (k0), &ldsA[buf][(w * 2 + 0) * 16 * BK]);        \
    gload16(gA1 + (k0), &ldsA[buf][(w * 2 + 1) * 16 * BK]);        \
    gload16(gB0 + (k0), &ldsB[buf][(w * 2 + 0) * 16 * BK]);        \
    gload16(gB1 + (k0), &ldsB[buf][(w * 2 + 1) * 16 * BK]);        \
  } while (0)

  STAGE2(0, 0);
  __syncthreads();
  int buf = 0;
  const int ko = (lane >> 4) * 8;
  const int wm = (w >> 1) * 64, wn = (w & 1) * 64;
  for (int kt = 0; kt < FF_DIM / BK; ++kt) {
    if (kt + 1 < FF_DIM / BK) STAGE2(buf ^ 1, (kt + 1) * BK);
    bf16x8 a[4], b[4];
#pragma unroll
    for (int mi = 0; mi < 4; ++mi)
      a[mi] = *(const bf16x8*)&ldsA[buf][(wm + mi * 16 + (lane & 15)) * BK + ko];
#pragma unroll
    for (int ni = 0; ni < 4; ++ni)
      b[ni] = *(const bf16x8*)&ldsB[buf][(wn + ni * 16 + (lane & 15)) * BK + ko];
#pragma unroll
    for (int mi = 0; mi < 4; ++mi)
#pragma unroll
      for (int ni = 0; ni < 4; ++ni)
        acc[mi][ni] = __builtin_amdgcn_mfma_f32_16x16x32_bf16(a[mi], b[ni], acc[mi][ni], 0, 0, 0);
    __syncthreads();
    buf ^= 1;
  }

  const float* bo = b_out + (size_t)e * H_DIM;
#pragma unroll
  for (int mi = 0; mi < 4; ++mi) {
#pragma unroll
    for (int i = 0; i < 4; ++i) {
      int mrow = mt * 128 + wm + mi * 16 + (lane >> 4) * 4 + i;
      if (mrow < cnt) {
        int slot = base + mrow;
        int t = tok_list[slot];
        float wt = w_list[slot];
#pragma unroll
        for (int ni = 0; ni < 4; ++ni) {
          int h = n0 + wn + ni * 16 + (lane & 15);
          atomicAdd(&out[(size_t)t * H_DIM + h], wt * (acc[mi][ni][i] + bo[h]));
        }
      }
    }
  }
}

// ---------------- aux loss finalize ----------------
__global__ void finalize_kernel(const float* __restrict__ imp, const int* __restrict__ pos_cnt,
                                float* __restrict__ out_aux) {
  if (threadIdx.x == 0) {
    float s = 0.f;
    for (int p = 0; p < TOPK; ++p)
      s += (imp[p] / (float)S_TOK) * ((float)pos_cnt[p] / (float)S_TOK);
    *out_aux = AUXC * (float)E_NUM * s;
  }
}

extern "C" void kernel_launch(void* const* d_in, const int* in_sizes, int n_in,
                              void* d_out, int out_size, void* d_ws, size_t ws_size,
                              hipStream_t stream) {
  const float* x     = (const float*)d_in[0];
  const float* W_in  = (const float*)d_in[1];
  const float* b_in  = (const float*)d_in[2];
  const float* W_out = (const float*)d_in[3];
  const float* b_out = (const float*)d_in[4];
  const float* rw    = (const float*)d_in[5];
  const float* rb    = (const float*)d_in[6];
  float* out = (float*)d_out;

  char* ws = (char*)d_ws;
  size_t off = 0;
  auto alloc = [&](size_t bytes) {
    void* p = ws + off;
    off = (off + bytes + 255) & ~(size_t)255;
    return p;
  };
  unsigned short* xb    = (unsigned short*)alloc((size_t)S_TOK * H_DIM * 2);
  unsigned short* winT  = (unsigned short*)alloc((size_t)E_NUM * 2 * FF_DIM * H_DIM * 2);
  unsigned short* woutT = (unsigned short*)alloc((size_t)E_NUM * H_DIM * FF_DIM * 2);
  unsigned short* act   = (unsigned short*)alloc((size_t)S_TOK * TOPK * FF_DIM * 2);
  float* logits  = (float*)alloc((size_t)S_TOK * E_NUM * 4);
  int*   topk_i  = (int*)alloc(S_TOK * TOPK * 4);
  float* topk_w  = (float*)alloc(S_TOK * TOPK * 4);
  int*   tok_list= (int*)alloc(S_TOK * TOPK * 4);
  float* w_list  = (float*)alloc(S_TOK * TOPK * 4);
  // zeroed control block: counts[16], cursor[16], pos_cnt[16] ints, imp[16] floats
  int* ctrl = (int*)alloc(64 * 4);
  int* counts = ctrl;
  int* cursor = ctrl + 16;
  int* pos_cnt = ctrl + 32;
  float* imp = (float*)(ctrl + 48);
  int* offsets = (int*)alloc(32 * 4);

  hipMemsetAsync(d_out, 0, (size_t)out_size * sizeof(float), stream);
  hipMemsetAsync(ctrl, 0, 64 * 4, stream);

  logits_kernel<<<S_TOK / 4, 256, 0, stream>>>(x, rw, rb, logits);
  convert_x_kernel<<<(S_TOK * H_DIM / 4) / 256, 256, 0, stream>>>(x, xb);
  transpose_kernel<<<dim3(2 * FF_DIM / 64, H_DIM / 64, E_NUM), 256, 0, stream>>>(W_in, winT, H_DIM, 2 * FF_DIM);
  transpose_kernel<<<dim3(H_DIM / 64, FF_DIM / 64, E_NUM), 256, 0, stream>>>(W_out, woutT, FF_DIM, H_DIM);
  topk_kernel<<<S_TOK / 256, 256, 0, stream>>>(logits, topk_i, topk_w, counts, imp, pos_cnt);
  scan_kernel<<<1, 64, 0, stream>>>(counts, offsets);
  assign_kernel<<<S_TOK / 256, 256, 0, stream>>>(topk_i, topk_w, offsets, cursor, tok_list, w_list);
  gemm1_kernel<<<dim3(FF_DIM / 64, S_TOK / 128, E_NUM), 256, 0, stream>>>(xb, winT, b_in, offsets, tok_list, act);
  gemm2_kernel<<<dim3(H_DIM / 128, S_TOK / 128, E_NUM), 256, 0, stream>>>(act, woutT, b_out, offsets, tok_list, w_list, out);
  finalize_kernel<<<1, 64, 0, stream>>>(imp, pos_cnt, out + (size_t)S_TOK * H_DIM);
}